// Round 4
// baseline (312.247 us; speedup 1.0000x reference)
//
#include <hip/hip_runtime.h>
#include <hip/hip_bf16.h>

#define RR 100
#define MID 256
#define NN 384
#define KP 128   // rank padded to 128 (zeros in r=100..127)

typedef __attribute__((ext_vector_type(8))) __bf16 bf16x8;
typedef __attribute__((ext_vector_type(4))) float floatx4;
typedef unsigned short ushort_t;

// Swizzled LDS offset (elements) for row-major [128][KP] bf16 tiles stored as
// 16 chunks of 8 bf16 per row; chunk index XOR'd with (row&15) so that
// MFMA fragment reads (16 rows x same chunk) spread across all 32 banks.
#define SW(row, ch) ((((row) << 7)) + ((((ch) ^ ((row) & 15))) << 3))

__device__ __forceinline__ ushort_t f2bf(float f) {
  __hip_bfloat16 h = __float2bfloat16(f);
  return __builtin_bit_cast(ushort_t, h);
}

// ---------------- Factor nets (all three in one launch) ----------------
// blockIdx.x = row i (0..383), blockIdx.y = net (0=A, 1=B, 2=C).
// A written fp32 [384][128]; B written bf16 [384][128] (B no longer carries
// the fold, so it is pre-rounded once); C written fp32 [384][128] (the fold
// A*C happens in the contraction kernel at fp32, single rounding).
__global__ __launch_bounds__(256) void factors_kernel(
    const float* __restrict__ xA, const float* __restrict__ xB,
    const float* __restrict__ xC,
    const float* __restrict__ AW1, const float* __restrict__ Ab1,
    const float* __restrict__ AW2, const float* __restrict__ Ab2,
    const float* __restrict__ BW1, const float* __restrict__ Bb1,
    const float* __restrict__ BW2, const float* __restrict__ Bb2,
    const float* __restrict__ CW1, const float* __restrict__ Cb1,
    const float* __restrict__ CW2, const float* __restrict__ Cb2,
    const float* __restrict__ CW3, const float* __restrict__ Cb3,
    float* __restrict__ Af, ushort_t* __restrict__ Bbf,
    float* __restrict__ Cf) {
  __shared__ float h[MID];
  __shared__ float h2[MID];
  const int i = blockIdx.x;
  const int net = blockIdx.y;
  const int t = threadIdx.x;

  const float* x  = (net == 0) ? xA  : (net == 1) ? xB  : xC;
  const float* W1 = (net == 0) ? AW1 : (net == 1) ? BW1 : CW1;
  const float* b1 = (net == 0) ? Ab1 : (net == 1) ? Bb1 : Cb1;

  const float xv = x[i];
  h[t] = sinf(1.5f * (xv * W1[t] + b1[t]));
  __syncthreads();

  const float* hlast = h;
  if (net == 2) {  // block-uniform branch
    float acc = Cb2[t];
    const float* __restrict__ w = &CW2[t * MID];
#pragma unroll 4
    for (int m = 0; m < MID; m += 4) {
      const float4 wv = *(const float4*)&w[m];
      const float4 hv = *(const float4*)&h[m];
      acc += hv.x * wv.x;
      acc += hv.y * wv.y;
      acc += hv.z * wv.z;
      acc += hv.w * wv.w;
    }
    h2[t] = sinf(1.5f * acc);
    __syncthreads();
    hlast = h2;
  }

  const float* W2 = (net == 0) ? AW2 : (net == 1) ? BW2 : CW3;
  const float* b2 = (net == 0) ? Ab2 : (net == 1) ? Bb2 : Cb3;

  if (t < KP) {
    float v = 0.0f;
    if (t < RR) {
      float acc = b2[t];
      const float* __restrict__ w = &W2[t * MID];
#pragma unroll 4
      for (int m = 0; m < MID; m += 4) {
        const float4 wv = *(const float4*)&w[m];
        const float4 hv = *(const float4*)&hlast[m];
        acc += hv.x * wv.x;
        acc += hv.y * wv.y;
        acc += hv.z * wv.z;
        acc += hv.w * wv.w;
      }
      v = acc;
    }
    if (net == 0)      Af[i * KP + t] = v;
    else if (net == 1) Bbf[i * KP + t] = f2bf(v);
    else               Cf[i * KP + t] = v;
  }
}

// ---------------- CP contraction via bf16 MFMA ----------------
// Restructured: block = (k-tile, i), computes the FULL j-strip
// out[i, 0:384, k0:k0+128].
//  * fold AC[k,r] = bf16(A[i,r]*C[k,r]) ONCE per block into swizzled LDS
//    (was: fold W per (i,j0,k0) block -> 3x less fold VALU per i).
//  * B fragments read directly from global bf16 (L2-resident 96 KB,
//    full-line 16-row x 64 B gathers), no per-i dependence.
//  * inner loop over 3 j-tiles with NO barriers: stores of tile n overlap
//    loads+MFMA of tile n+1.
//  * LDS 32 KB, target 3 blocks/CU.
// Numerics: bf16(A*C) x bf16(B) -- same two-rounding error profile as the
// previous bf16(A*B) x bf16(C); f32 MFMA accumulation unchanged.
__global__ __launch_bounds__(256, 3) void cp_mfma(
    const float* __restrict__ Af, const ushort_t* __restrict__ Bbf,
    const float* __restrict__ Cf, float* __restrict__ out) {
  __shared__ ushort_t ACt[128 * KP];  // 32 KB

  const int i  = blockIdx.y;
  const int k0 = blockIdx.x * 128;
  const int t  = threadIdx.x;

  // ---- fold AC tile into LDS: 2 threads per k-row, 64 r's each ----
  {
    const int kx = t >> 1;
    const int hh = t & 1;
    const float* __restrict__ arow = Af + (size_t)i * KP + hh * 64;
    const float* __restrict__ crow = Cf + (size_t)(k0 + kx) * KP + hh * 64;
#pragma unroll
    for (int c = 0; c < 8; ++c) {
      const float4 a0 = *(const float4*)(arow + c * 8);
      const float4 a1 = *(const float4*)(arow + c * 8 + 4);
      const float4 c0 = *(const float4*)(crow + c * 8);
      const float4 c1 = *(const float4*)(crow + c * 8 + 4);
      uint4 wv;
      wv.x = (unsigned)f2bf(a0.x * c0.x) | ((unsigned)f2bf(a0.y * c0.y) << 16);
      wv.y = (unsigned)f2bf(a0.z * c0.z) | ((unsigned)f2bf(a0.w * c0.w) << 16);
      wv.z = (unsigned)f2bf(a1.x * c1.x) | ((unsigned)f2bf(a1.y * c1.y) << 16);
      wv.w = (unsigned)f2bf(a1.z * c1.z) | ((unsigned)f2bf(a1.w * c1.w) << 16);
      *(uint4*)&ACt[SW(kx, hh * 8 + c)] = wv;
    }
  }
  __syncthreads();

  // ---- MFMA over 3 j-tiles ----
  const int lane = t & 63;
  const int w    = t >> 6;
  const int wj   = (w & 1) * 64;
  const int wk   = (w >> 1) * 64;
  const int m16  = lane & 15;
  const int g    = lane >> 4;

  const size_t ibase = (size_t)i * NN * NN;

#pragma unroll 1
  for (int jt = 0; jt < 3; ++jt) {
    const int jb = jt * 128 + wj;

    // acc[kf][jf]: D col = j (m16), D row = k (g*4 + reg)
    floatx4 acc[4][4];
#pragma unroll
    for (int kf = 0; kf < 4; ++kf)
#pragma unroll
      for (int jf = 0; jf < 4; ++jf) acc[kf][jf] = (floatx4)0.0f;

#pragma unroll
    for (int ks = 0; ks < 4; ++ks) {
      const int rc = (ks * 4 + g) * 8;  // this lane's 8-wide r-chunk

      bf16x8 cfr[4], bfr[4];
#pragma unroll
      for (int f = 0; f < 4; ++f) {
        cfr[f] = *(const bf16x8*)&ACt[SW(wk + f * 16 + m16, ks * 4 + g)];
        bfr[f] = *(const bf16x8*)&Bbf[(size_t)(jb + f * 16 + m16) * KP + rc];
      }
#pragma unroll
      for (int jf = 0; jf < 4; ++jf)
#pragma unroll
        for (int kf = 0; kf < 4; ++kf)
          acc[kf][jf] = __builtin_amdgcn_mfma_f32_16x16x32_bf16(
              cfr[kf], bfr[jf], acc[kf][jf], 0, 0, 0);
    }

    // epilogue: lane owns out[i, jb+jf*16+m16, k0+wk+kf*16+g*4 .. +3]
#pragma unroll
    for (int kf = 0; kf < 4; ++kf) {
      const int k = k0 + wk + kf * 16 + g * 4;
#pragma unroll
      for (int jf = 0; jf < 4; ++jf) {
        const int j = jb + jf * 16 + m16;
        *(floatx4*)&out[ibase + (size_t)j * NN + k] = acc[kf][jf];
      }
    }
  }
}

extern "C" void kernel_launch(void* const* d_in, const int* in_sizes, int n_in,
                              void* d_out, int out_size, void* d_ws, size_t ws_size,
                              hipStream_t stream) {
  const float* A_input = (const float*)d_in[0];
  const float* B_input = (const float*)d_in[1];
  const float* C_input = (const float*)d_in[2];
  const float* A_W1 = (const float*)d_in[3];
  const float* A_b1 = (const float*)d_in[4];
  const float* A_W2 = (const float*)d_in[5];
  const float* A_b2 = (const float*)d_in[6];
  const float* B_W1 = (const float*)d_in[7];
  const float* B_b1 = (const float*)d_in[8];
  const float* B_W2 = (const float*)d_in[9];
  const float* B_b2 = (const float*)d_in[10];
  const float* C_W1 = (const float*)d_in[11];
  const float* C_b1 = (const float*)d_in[12];
  const float* C_W2 = (const float*)d_in[13];
  const float* C_b2 = (const float*)d_in[14];
  const float* C_W3 = (const float*)d_in[15];
  const float* C_b3 = (const float*)d_in[16];

  // ws layout: Af fp32 [384][128] | Cf fp32 [384][128] | Bbf bf16 [384][128]
  float* Af = (float*)d_ws;                       // 196,608 B
  float* Cf = Af + NN * KP;                       // 196,608 B
  ushort_t* Bbf = (ushort_t*)(Cf + NN * KP);      //  98,304 B  (total 480 KB)

  dim3 fgrid(NN, 3);
  factors_kernel<<<fgrid, 256, 0, stream>>>(
      A_input, B_input, C_input,
      A_W1, A_b1, A_W2, A_b2,
      B_W1, B_b1, B_W2, B_b2,
      C_W1, C_b1, C_W2, C_b2, C_W3, C_b3,
      Af, Bbf, Cf);

  dim3 grid(NN / 128, NN);  // (k-tiles, i)
  cp_mfma<<<grid, 256, 0, stream>>>(Af, Bbf, Cf, (float*)d_out);
}